// Round 3
// baseline (573.604 us; speedup 1.0000x reference)
//
#include <hip/hip_runtime.h>

#define B_IMG 8
#define D_DIM 32
#define NPIX 262144          // 512*512
#define K_CL 16

// ---- k_sums geometry ----
#define CHUNK_S 4096
#define CHUNKS_S (NPIX / CHUNK_S)       // 64
#define AST 257                          // float4 stride pad (bank spread)

// ---- k_var geometry ----
#define CHUNK_V 1024
#define CHUNKS_V (NPIX / CHUNK_V)       // 256
#define VST 264                          // scalar stride pad

__device__ __forceinline__ float wave_sum(float v) {
#pragma unroll
  for (int off = 32; off > 0; off >>= 1) v += __shfl_xor(v, off, 64);
  return v;
}

template <int NC>
__device__ __forceinline__ float4 wave_sum4(float4 v) {
#pragma unroll
  for (int off = 32; off > 0; off >>= 1) {
    v.x += __shfl_xor(v.x, off, 64);
    if (NC == 4) {
      v.y += __shfl_xor(v.y, off, 64);
      v.z += __shfl_xor(v.z, off, 64);
      v.w += __shfl_xor(v.w, off, 64);
    }
  }
  return v;
}

// Reduce the 16 float4 rows of acc4 (256 wide), zero them, atomically add
// NC components into base[r*rstride + c]. 4 waves x 4 rows.
template <int NC>
__device__ __forceinline__ void flush4(float4 (*acc)[AST], int tid,
                                       float* base, int rstride) {
  const int w = tid >> 6, lane = tid & 63;
#pragma unroll
  for (int rr = 0; rr < 4; rr++) {
    const int r = (w << 2) | rr;
    float4 s = make_float4(0.f, 0.f, 0.f, 0.f);
#pragma unroll
    for (int q = 0; q < 4; q++) {
      float4 v = acc[r][(q << 6) | lane];
      acc[r][(q << 6) | lane] = make_float4(0.f, 0.f, 0.f, 0.f);
      s.x += v.x; s.y += v.y; s.z += v.z; s.w += v.w;
    }
    s = wave_sum4<NC>(s);
    if (lane == 0) {
      unsafeAtomicAdd(base + r * rstride + 0, s.x);
      if (NC == 4) {
        unsafeAtomicAdd(base + r * rstride + 1, s.y);
        unsafeAtomicAdd(base + r * rstride + 2, s.z);
        unsafeAtomicAdd(base + r * rstride + 3, s.w);
      }
    }
  }
}

// ---------------- Pass A: counts + per-(k,d) sums, 4 channels at a time ----------------
__global__ __launch_bounds__(256) void k_sums(const float* __restrict__ emb,
                                              const int* __restrict__ gt,
                                              float* __restrict__ sums,
                                              float* __restrict__ counts) {
  __shared__ float4 acc4[K_CL][AST];     // 65,792 B -> 2 blocks/CU
  const int tid = threadIdx.x;
  const int b = blockIdx.x >> 6;         // CHUNKS_S == 64
  const int chunk = blockIdx.x & (CHUNKS_S - 1);
  const int base = chunk * CHUNK_S;

  int lb[16];
  {
    const int4* lp = (const int4*)(gt + (size_t)b * NPIX + base);
#pragma unroll
    for (int h = 0; h < 4; h++) {
      int4 a = lp[tid + (h << 8)];
      lb[h * 4 + 0] = a.x; lb[h * 4 + 1] = a.y;
      lb[h * 4 + 2] = a.z; lb[h * 4 + 3] = a.w;
    }
  }
#pragma unroll
  for (int k = 0; k < K_CL; k++) acc4[k][tid] = make_float4(0.f, 0.f, 0.f, 0.f);
  __syncthreads();

  // counts into .x
#pragma unroll
  for (int j = 0; j < 16; j++) acc4[lb[j]][tid].x += 1.0f;
  __syncthreads();
  flush4<1>(acc4, tid, counts + b * K_CL, 1);
  __syncthreads();

  for (int g = 0; g < 8; g++) {          // channel groups of 4
    const float* eb = emb + ((size_t)b * D_DIM + g * 4) * NPIX + base;
#pragma unroll
    for (int h = 0; h < 4; h++) {        // 4 pixels per batch, 4 batches
      float4 v[4];
#pragma unroll
      for (int d = 0; d < 4; d++)
        v[d] = ((const float4*)(eb + (size_t)d * NPIX))[tid + (h << 8)];
#pragma unroll
      for (int c = 0; c < 4; c++) {
        const int l = lb[h * 4 + c];
        float4 t;
        t.x = ((const float*)&v[0])[c];
        t.y = ((const float*)&v[1])[c];
        t.z = ((const float*)&v[2])[c];
        t.w = ((const float*)&v[3])[c];
        float4 old = acc4[l][tid];
        old.x += t.x; old.y += t.y; old.z += t.z; old.w += t.w;
        acc4[l][tid] = old;
      }
    }
    __syncthreads();
    flush4<4>(acc4, tid, sums + (size_t)b * K_CL * D_DIM + g * 4, D_DIM);
    __syncthreads();
  }
}

// ------------- Pass C: variance loss + distance/reg per image -------------
__global__ __launch_bounds__(256) void k_var(const float* __restrict__ emb,
                                             const int* __restrict__ gt,
                                             const float* __restrict__ sums,
                                             const float* __restrict__ counts,
                                             float* __restrict__ var_sums,
                                             float* __restrict__ dist_reg) {
  __shared__ float acc[K_CL][VST];       // 16.9 KB
  __shared__ float4 mk4[K_CL][9];        // means, transposed + padded
  __shared__ float msq[K_CL];
  __shared__ float red4[4];
  const int tid = threadIdx.x;
  const int b = blockIdx.x >> 8;         // CHUNKS_V == 256
  const int chunk = blockIdx.x & (CHUNKS_V - 1);
  const int base = chunk * CHUNK_V;

  // rebuild means: mk4 row stride 9 float4 = 36 floats; offset = k*36 + d
  float* mkf = (float*)mk4;
#pragma unroll
  for (int e0 = 0; e0 < 2; e0++) {
    const int e = tid + (e0 << 8);       // e = k*32 + d
    const int k = e >> 5, d = e & 31;
    const float c = fmaxf(counts[b * K_CL + k], 1.0f);
    mkf[k * 36 + d] = sums[(size_t)b * K_CL * D_DIM + e] / c;
  }
#pragma unroll
  for (int k = 0; k < K_CL; k++) acc[k][tid] = 0.f;
  __syncthreads();
  if (tid < K_CL) {
    float s = 0.f;
#pragma unroll
    for (int g = 0; g < 8; g++) {
      float4 m = mk4[tid][g];
      s = fmaf(m.x, m.x, s); s = fmaf(m.y, m.y, s);
      s = fmaf(m.z, m.z, s); s = fmaf(m.w, m.w, s);
    }
    msq[tid] = s;
  }
  __syncthreads();

  // one block per image: O(K^2 D) distance loss + reg loss
  if (chunk == 0) {
    const int i = tid >> 4, j = tid & 15;
    float sq = 0.f;
#pragma unroll
    for (int g = 0; g < 8; g++) {
      float4 mi = mk4[i][g], mj = mk4[j][g];
      float dx = mi.x - mj.x, dy = mi.y - mj.y, dz = mi.z - mj.z, dw = mi.w - mj.w;
      sq = fmaf(dx, dx, sq); sq = fmaf(dy, dy, sq);
      sq = fmaf(dz, dz, sq); sq = fmaf(dw, dw, sq);
    }
    float contrib = 0.f;
    if (i < j) {
      const float h = fmaxf(3.0f - sqrtf(sq), 0.0f);   // 2*DIST_THETA
      contrib = h * h;
    }
    const float tot = wave_sum(contrib);
    if ((tid & 63) == 0) red4[tid >> 6] = tot;
    __syncthreads();
    if (tid == 0) {
      const float dist = (red4[0] + red4[1] + red4[2] + red4[3]) * (1.0f / 240.0f);
      float reg = 0.f;
#pragma unroll
      for (int k = 0; k < K_CL; k++) reg += sqrtf(msq[k]);
      dist_reg[b] = dist + 0.001f * (reg * (1.0f / 16.0f));
    }
  }

  int lb[4];
  {
    const int4* lp = (const int4*)(gt + (size_t)b * NPIX + base);
    int4 a = lp[tid];
    lb[0] = a.x; lb[1] = a.y; lb[2] = a.z; lb[3] = a.w;
  }
  float a[4] = {0.f, 0.f, 0.f, 0.f};

  // d2 = sum_d x^2 - 2 x*m + ||m||^2, channels in groups of 4
#pragma unroll 2
  for (int g = 0; g < 8; g++) {
    const float* eb = emb + ((size_t)b * D_DIM + g * 4) * NPIX + base;
    float4 v[4];
#pragma unroll
    for (int d = 0; d < 4; d++)
      v[d] = ((const float4*)(eb + (size_t)d * NPIX))[tid];
#pragma unroll
    for (int j = 0; j < 4; j++) {
      const float4 m4 = mk4[lb[j]][g];
#pragma unroll
      for (int d = 0; d < 4; d++) {
        const float x = ((const float*)&v[d])[j];
        const float mm = ((const float*)&m4)[d];
        a[j] = fmaf(x, x - 2.0f * mm, a[j]);
      }
    }
  }
#pragma unroll
  for (int j = 0; j < 4; j++) {
    const float d2 = a[j] + msq[lb[j]];
    const float dd = sqrtf(fmaxf(d2, 0.f));
    const float h = fmaxf(dd - 0.5f, 0.f);             // VAR_THETA
    acc[lb[j]][tid] += h * h;
  }
  __syncthreads();

  // scalar flush of acc rows -> var_sums
  const int w = tid >> 6, lane = tid & 63;
#pragma unroll
  for (int rr = 0; rr < 4; rr++) {
    const int r = (w << 2) | rr;
    float4 vv = *(float4*)(&acc[r][lane << 2]);
    float tot = wave_sum(vv.x + vv.y + vv.z + vv.w);
    if (lane == 0) unsafeAtomicAdd(&var_sums[b * K_CL + r], tot);
  }
}

// ---------------- Final combine ----------------
__global__ __launch_bounds__(128) void k_final(const float* __restrict__ counts,
                                               const float* __restrict__ var_sums,
                                               const float* __restrict__ dist_reg,
                                               float* __restrict__ out) {
  const int t = threadIdx.x;             // t = b*16 + k
  float pc = 0.f;
  if (t < B_IMG * K_CL) pc = var_sums[t] / fmaxf(counts[t], 1.0f);
#pragma unroll
  for (int off = 8; off > 0; off >>= 1) pc += __shfl_xor(pc, off, 64);
  __shared__ float lbl[B_IMG];
  if (t < B_IMG * K_CL && (t & 15) == 0) {
    const int b = t >> 4;
    lbl[b] = pc * (1.0f / 16.0f) + dist_reg[b];
  }
  __syncthreads();
  if (t == 0) {
    float s = 0.f;
#pragma unroll
    for (int b = 0; b < B_IMG; b++) s += lbl[b];
    out[0] = s * (1.0f / B_IMG);
  }
}

extern "C" void kernel_launch(void* const* d_in, const int* in_sizes, int n_in,
                              void* d_out, int out_size, void* d_ws, size_t ws_size,
                              hipStream_t stream) {
  const float* emb = (const float*)d_in[0];
  const int* gt = (const int*)d_in[1];
  float* out = (float*)d_out;

  float* sums = (float*)d_ws;                           // 4096 floats
  float* counts = sums + B_IMG * K_CL * D_DIM;          // 128
  float* var_sums = counts + B_IMG * K_CL;              // 128
  float* dist_reg = var_sums + B_IMG * K_CL;            // 8

  const size_t ws_floats = B_IMG * K_CL * D_DIM + 2 * B_IMG * K_CL + B_IMG;
  hipMemsetAsync(d_ws, 0, ws_floats * sizeof(float), stream);

  k_sums<<<dim3(B_IMG * CHUNKS_S), dim3(256), 0, stream>>>(emb, gt, sums, counts);
  k_var<<<dim3(B_IMG * CHUNKS_V), dim3(256), 0, stream>>>(emb, gt, sums, counts,
                                                          var_sums, dist_reg);
  k_final<<<dim3(1), dim3(128), 0, stream>>>(counts, var_sums, dist_reg, out);
}